// Round 1
// baseline (1393.213 us; speedup 1.0000x reference)
//
#include <hip/hip_runtime.h>

#define T_LEN 1024
#define IN_DIM 128
#define HID 64

typedef __attribute__((ext_vector_type(8))) short short8;
typedef __attribute__((ext_vector_type(4))) float floatx4;
typedef __attribute__((ext_vector_type(2))) float floatx2;

__device__ __forceinline__ unsigned short f2bf(float v) {
    union { float f; unsigned u; } a; a.f = v;
    unsigned r = a.u + 0x7FFFu + ((a.u >> 16) & 1u);  // RNE, no NaN inputs here
    return (unsigned short)(r >> 16);
}

__device__ __forceinline__ short8 cvt8(const float* p) {
    short8 r;
#pragma unroll
    for (int j = 0; j < 8; ++j) r[j] = (short)f2bf(p[j]);
    return r;
}

__device__ __forceinline__ float sigm(float x) { return 1.0f / (1.0f + __expf(-x)); }
__device__ __forceinline__ float tanh_(float x) { return 2.0f / (1.0f + __expf(-2.0f * x)) - 1.0f; }

// One block = 4 batch rows of one direction. 256 blocks = 2 dirs * 128.
// Wave w owns N-tiles {w, 4+w, 8+w, 12+w} -> gate classes i,f,g,o for units j=16w..16w+15.
__global__ __launch_bounds__(256, 1) void lstm_bidir(
    const float* __restrict__ x,
    const float* __restrict__ WihF, const float* __restrict__ WhhF, const float* __restrict__ bF,
    const float* __restrict__ WihB, const float* __restrict__ WhhB, const float* __restrict__ bB,
    float* __restrict__ out)
{
    const int tid  = threadIdx.x;
    const int w    = tid >> 6;       // wave id 0..3
    const int lane = tid & 63;
    const int nloc = lane & 15;      // m (A rows) / n (B cols) fragment index
    const int quad = lane >> 4;      // k = quad*8 + j
    const int bid  = blockIdx.x;
    const int dir  = bid & 1;
    const int b0   = (bid >> 1) * 4;

    const float* Wih  = dir ? WihB : WihF;
    const float* Whh  = dir ? WhhB : WhhF;
    const float* bias = dir ? bB   : bF;

    // LDS: double-buffered x tile (16 rows x 128 bf16, pad to 136) and h tile (16 x 64, pad to 72).
    // Row strides 136/72 ushorts keep 16B alignment for b128 reads and give a 2-way (free) bank pattern.
    __shared__ unsigned short x_s[2][16 * 136];
    __shared__ unsigned short h_s[2][16 * 136 / 2 < 16 * 72 ? 16 * 72 : 16 * 72];  // 16*72

    for (int i = tid; i < 2 * 16 * 136; i += 256) ((unsigned short*)x_s)[i] = 0;
    for (int i = tid; i < 2 * 16 * 72;  i += 256) ((unsigned short*)h_s)[i] = 0;

    // ---- Preload weight B-fragments into registers (one-time, ~96 VGPRs) ----
    short8 wihf[4][4];  // [gate class][k-frag of 32]
    short8 whhf[4][2];
    float  bv[4];
#pragma unroll
    for (int gc = 0; gc < 4; ++gc) {
        const int row = gc * 64 + w * 16 + nloc;   // gate index in [0,256)
        bv[gc] = bias[row];
#pragma unroll
        for (int kf = 0; kf < 4; ++kf)
            wihf[gc][kf] = cvt8(Wih + row * IN_DIM + kf * 32 + quad * 8);
#pragma unroll
        for (int kf = 0; kf < 2; ++kf)
            whhf[gc][kf] = cvt8(Whh + row * HID + kf * 32 + quad * 8);
    }

    // ---- x staging: 256 threads x float2 = 4 rows x 128 ----
    const int sr = tid >> 6;            // staging row 0..3
    const int sk = (tid & 63) * 2;      // staging k
    const float* xrow = x + (size_t)(b0 + sr) * T_LEN * IN_DIM + sk;

    auto tmap = [&](int s) {
        int ss = s < T_LEN - 1 ? s : T_LEN - 1;
        return dir ? (T_LEN - 1 - ss) : ss;
    };

    // stage x(step 0) into buffer 0
    {
        floatx2 v = *(const floatx2*)(xrow + (size_t)tmap(0) * IN_DIM);
        unsigned pack = (unsigned)f2bf(v.x) | ((unsigned)f2bf(v.y) << 16);
        *(unsigned*)&x_s[0][sr * 136 + sk] = pack;
    }
    // prefetch x(step 1)
    floatx2 pfA = *(const floatx2*)(xrow + (size_t)tmap(1) * IN_DIM);
    floatx2 pfB;

    float c[4] = {0.f, 0.f, 0.f, 0.f};

    __syncthreads();

    float* outcol = out + (size_t)dir * HID + w * 16 + nloc;  // + row*T*128 + t*128 later

    auto step = [&](int t, floatx2& useReg, floatx2& loadReg) {
        const int buf = t & 1;

        // issue prefetch for x(t+2) early (consumed at end of NEXT step)
        loadReg = *(const floatx2*)(xrow + (size_t)tmap(t + 2) * IN_DIM);

        // A-fragments from LDS (rows 4..15 are zero)
        short8 xa[4], ha[2];
        const unsigned short* xb = &x_s[buf][nloc * 136 + quad * 8];
#pragma unroll
        for (int kf = 0; kf < 4; ++kf) xa[kf] = *(const short8*)(xb + kf * 32);
        const unsigned short* hb = &h_s[buf][nloc * 72 + quad * 8];
#pragma unroll
        for (int kf = 0; kf < 2; ++kf) ha[kf] = *(const short8*)(hb + kf * 32);

        floatx4 acc[4];
#pragma unroll
        for (int gc = 0; gc < 4; ++gc) acc[gc] = (floatx4){bv[gc], bv[gc], bv[gc], bv[gc]};
#pragma unroll
        for (int kf = 0; kf < 4; ++kf)
#pragma unroll
            for (int gc = 0; gc < 4; ++gc)
                acc[gc] = __builtin_amdgcn_mfma_f32_16x16x32_bf16(xa[kf], wihf[gc][kf], acc[gc], 0, 0, 0);
#pragma unroll
        for (int kf = 0; kf < 2; ++kf)
#pragma unroll
            for (int gc = 0; gc < 4; ++gc)
                acc[gc] = __builtin_amdgcn_mfma_f32_16x16x32_bf16(ha[kf], whhf[gc][kf], acc[gc], 0, 0, 0);

        const int tg = tmap(t);
        // C/D layout: col=lane&15, row=(lane>>4)*4+reg -> real rows 0..3 live in lanes 0..15
        if (lane < 16) {
#pragma unroll
            for (int r = 0; r < 4; ++r) {
                float iv = sigm(acc[0][r]);
                float fv = sigm(acc[1][r]);
                float gv = tanh_(acc[2][r]);
                float ov = sigm(acc[3][r]);
                c[r] = fv * c[r] + iv * gv;
                float hv = ov * tanh_(c[r]);
                outcol[((size_t)(b0 + r) * T_LEN + tg) * 128] = hv;
                h_s[buf ^ 1][r * 72 + w * 16 + nloc] = f2bf(hv);
            }
        }
        // stage x(t+1) (loaded during previous step) into the other buffer
        {
            unsigned pack = (unsigned)f2bf(useReg.x) | ((unsigned)f2bf(useReg.y) << 16);
            *(unsigned*)&x_s[buf ^ 1][sr * 136 + sk] = pack;
        }
        __syncthreads();
    };

    for (int t = 0; t < T_LEN; t += 2) {
        step(t, pfA, pfB);
        step(t + 1, pfB, pfA);
    }
}

extern "C" void kernel_launch(void* const* d_in, const int* in_sizes, int n_in,
                              void* d_out, int out_size, void* d_ws, size_t ws_size,
                              hipStream_t stream) {
    const float* x    = (const float*)d_in[0];
    const float* WihF = (const float*)d_in[1];
    const float* WhhF = (const float*)d_in[2];
    const float* bF   = (const float*)d_in[3];
    const float* WihB = (const float*)d_in[4];
    const float* WhhB = (const float*)d_in[5];
    const float* bB   = (const float*)d_in[6];
    float* out = (float*)d_out;

    lstm_bidir<<<dim3(256), dim3(256), 0, stream>>>(x, WihF, WhhF, bF, WihB, WhhB, bB, out);
}

// Round 2
// 868.747 us; speedup vs baseline: 1.6037x; 1.6037x over previous
//
#include <hip/hip_runtime.h>

#define T_LEN 1024
#define IN_DIM 128
#define HID 64

typedef __attribute__((ext_vector_type(8))) short short8;
typedef __attribute__((ext_vector_type(4))) float floatx4;
typedef __attribute__((ext_vector_type(2))) float floatx2;

__device__ __forceinline__ unsigned short f2bf(float v) {
    union { float f; unsigned u; } a; a.f = v;
    unsigned r = a.u + 0x7FFFu + ((a.u >> 16) & 1u);  // RNE, no NaN inputs here
    return (unsigned short)(r >> 16);
}

__device__ __forceinline__ short8 cvt8(const float* p) {
    short8 r;
#pragma unroll
    for (int j = 0; j < 8; ++j) r[j] = (short)f2bf(p[j]);
    return r;
}

// fast sigmoid / tanh: v_exp_f32 (2^x) + v_rcp_f32, ~1 ulp each
#define LOG2E 1.44269504088896f
__device__ __forceinline__ float sigm(float x) {
    return __builtin_amdgcn_rcpf(1.0f + __builtin_amdgcn_exp2f(x * -LOG2E));
}
__device__ __forceinline__ float tanh_(float x) {
    return 2.0f * __builtin_amdgcn_rcpf(1.0f + __builtin_amdgcn_exp2f(x * -2.0f * LOG2E)) - 1.0f;
}

// One block = 4 batch rows of one direction. 256 blocks = 2 dirs * 128.
// Wave w owns gate classes i,f,g,o for units j=16w..16w+15.
// A-fragment rows are read REPLICATED (row = nloc>>2) so effective A rows are
// {r0 x4, r1 x4, r2 x4, r3 x4}; C row = quad*4+reg then means every lane
// (quad q, col n) holds gates for (batch row q, unit 16w+n) in all 4 acc regs
// -> full-wave epilogue with zero cross-lane traffic.
__global__ __launch_bounds__(256, 1) void lstm_bidir(
    const float* __restrict__ x,
    const float* __restrict__ WihF, const float* __restrict__ WhhF, const float* __restrict__ bF,
    const float* __restrict__ WihB, const float* __restrict__ WhhB, const float* __restrict__ bB,
    float* __restrict__ out)
{
    const int tid  = threadIdx.x;
    const int w    = tid >> 6;       // wave id 0..3
    const int lane = tid & 63;
    const int nloc = lane & 15;      // C col / B n index
    const int quad = lane >> 4;      // A/B k = quad*8 + j ; epilogue batch row
    const int bid  = blockIdx.x;
    const int dir  = bid & 1;
    const int b0   = (bid >> 1) * 4;

    const float* Wih  = dir ? WihB : WihF;
    const float* Whh  = dir ? WhhB : WhhF;
    const float* bias = dir ? bB   : bF;

    // LDS: double-buffered x tile (4 rows x 128 bf16, stride 136) and h tile
    // (4 x 64 bf16, stride 72). Strides keep 16B alignment for b128 reads.
    __shared__ unsigned short x_s[2][4 * 136];
    __shared__ unsigned short h_s[2][4 * 72];

    for (int i = tid; i < 2 * 4 * 72; i += 256) ((unsigned short*)h_s)[i] = 0;

    // ---- Preload weight B-fragments into registers (one-time, ~96 VGPRs) ----
    short8 wihf[4][4];  // [gate class][k-frag of 32]
    short8 whhf[4][2];
    float  bv[4];
#pragma unroll
    for (int gc = 0; gc < 4; ++gc) {
        const int row = gc * 64 + w * 16 + nloc;   // gate index in [0,256)
        bv[gc] = bias[row];
#pragma unroll
        for (int kf = 0; kf < 4; ++kf)
            wihf[gc][kf] = cvt8(Wih + row * IN_DIM + kf * 32 + quad * 8);
#pragma unroll
        for (int kf = 0; kf < 2; ++kf)
            whhf[gc][kf] = cvt8(Whh + row * HID + kf * 32 + quad * 8);
    }

    // ---- x staging: 256 threads x float2 = 4 rows x 128 ----
    const int sr = tid >> 6;            // staging row 0..3
    const int sk = (tid & 63) * 2;      // staging k
    const float* xrow = x + (size_t)(b0 + sr) * T_LEN * IN_DIM + sk;

    auto tmap = [&](int s) {
        int ss = s < T_LEN - 1 ? s : T_LEN - 1;
        return dir ? (T_LEN - 1 - ss) : ss;
    };

    // stage x(step 0) into buffer 0
    {
        floatx2 v = *(const floatx2*)(xrow + (size_t)tmap(0) * IN_DIM);
        unsigned pack = (unsigned)f2bf(v.x) | ((unsigned)f2bf(v.y) << 16);
        *(unsigned*)&x_s[0][sr * 136 + sk] = pack;
    }
    // prefetch x(step 1)
    floatx2 pfA = *(const floatx2*)(xrow + (size_t)tmap(1) * IN_DIM);
    floatx2 pfB;

    float c = 0.f;                       // cell state for (row=quad, unit=16w+nloc)

    __syncthreads();

    // epilogue output column: out[(b0+quad)*T*128 + t*128 + dir*64 + 16w + nloc]
    float* outcol = out + ((size_t)(b0 + quad) * T_LEN) * 128 + dir * HID + w * 16 + nloc;

    auto step = [&](int t, floatx2& useReg, floatx2& loadReg) {
        const int buf = t & 1;

        // issue prefetch for x(t+2) early (consumed at end of NEXT step)
        loadReg = *(const floatx2*)(xrow + (size_t)tmap(t + 2) * IN_DIM);

        // A-fragments from LDS, row replicated 4x (row = nloc>>2)
        short8 xa[4], ha[2];
        const unsigned short* xb = &x_s[buf][(nloc >> 2) * 136 + quad * 8];
#pragma unroll
        for (int kf = 0; kf < 4; ++kf) xa[kf] = *(const short8*)(xb + kf * 32);
        const unsigned short* hb = &h_s[buf][(nloc >> 2) * 72 + quad * 8];
#pragma unroll
        for (int kf = 0; kf < 2; ++kf) ha[kf] = *(const short8*)(hb + kf * 32);

        floatx4 acc[4];
#pragma unroll
        for (int gc = 0; gc < 4; ++gc) acc[gc] = (floatx4){bv[gc], bv[gc], bv[gc], bv[gc]};
#pragma unroll
        for (int kf = 0; kf < 4; ++kf)
#pragma unroll
            for (int gc = 0; gc < 4; ++gc)
                acc[gc] = __builtin_amdgcn_mfma_f32_16x16x32_bf16(xa[kf], wihf[gc][kf], acc[gc], 0, 0, 0);
#pragma unroll
        for (int kf = 0; kf < 2; ++kf)
#pragma unroll
            for (int gc = 0; gc < 4; ++gc)
                acc[gc] = __builtin_amdgcn_mfma_f32_16x16x32_bf16(ha[kf], whhf[gc][kf], acc[gc], 0, 0, 0);

        const int tg = tmap(t);
        // every lane: gates for (row=quad, unit=16w+nloc), replicated in regs -> use [0]
        {
            float iv = sigm(acc[0][0]);
            float fv = sigm(acc[1][0]);
            float gv = tanh_(acc[2][0]);
            float ov = sigm(acc[3][0]);
            c = fv * c + iv * gv;
            float hv = ov * tanh_(c);
            outcol[(size_t)tg * 128] = hv;
            h_s[buf ^ 1][quad * 72 + w * 16 + nloc] = f2bf(hv);
        }
        // stage x(t+1) (loaded during previous step) into the other buffer
        {
            unsigned pack = (unsigned)f2bf(useReg.x) | ((unsigned)f2bf(useReg.y) << 16);
            *(unsigned*)&x_s[buf ^ 1][sr * 136 + sk] = pack;
        }
        __syncthreads();
    };

    for (int t = 0; t < T_LEN; t += 2) {
        step(t, pfA, pfB);
        step(t + 1, pfB, pfA);
    }
}

extern "C" void kernel_launch(void* const* d_in, const int* in_sizes, int n_in,
                              void* d_out, int out_size, void* d_ws, size_t ws_size,
                              hipStream_t stream) {
    const float* x    = (const float*)d_in[0];
    const float* WihF = (const float*)d_in[1];
    const float* WhhF = (const float*)d_in[2];
    const float* bF   = (const float*)d_in[3];
    const float* WihB = (const float*)d_in[4];
    const float* WhhB = (const float*)d_in[5];
    const float* bB   = (const float*)d_in[6];
    float* out = (float*)d_out;

    lstm_bidir<<<dim3(256), dim3(256), 0, stream>>>(x, WihF, WhhF, bF, WihB, WhhB, bB, out);
}